// Round 4
// baseline (992.924 us; speedup 1.0000x reference)
//
#include <hip/hip_runtime.h>
#include <stdint.h>

// Swin block: B=64, H=W=56, C=128, HID=512, WS=7, NH=4, SHIFT=3
static constexpr int Bz   = 64;
static constexpr int HH   = 56, WWp = 56;
static constexpr int C    = 128, HID = 512;
static constexpr int L    = HH * WWp;        // 3136
static constexpr int M    = Bz * L;          // 200704
static constexpr int NWIN = Bz * 64;         // 4096 windows
static constexpr int NH   = 4;
static constexpr int SHIFT = 3;

typedef __bf16 bf16x8 __attribute__((ext_vector_type(8)));
typedef float  f32x4  __attribute__((ext_vector_type(4)));

__device__ __forceinline__ float bf2f(unsigned short u) {
    return __uint_as_float(((unsigned int)u) << 16);
}
__device__ __forceinline__ unsigned short f2bf(float f) {
    unsigned int u = __float_as_uint(f);
    return (unsigned short)((u + 0x7FFFu + ((u >> 16) & 1u)) >> 16);
}
__device__ __forceinline__ unsigned lds_addr(const void* p) {
    return (unsigned)(size_t)(__attribute__((address_space(3))) const char*)p;
}

// window-order row m -> original (b,l) row: roll(-SHIFT) + 7x7 partition.
__device__ __forceinline__ int win2orig(int m) {
    int w = m / 49, t = m - w * 49;
    int b = w >> 6, wi = (w >> 3) & 7, wj = w & 7;
    int ti = t / 7, tj = t - ti * 7;
    int i = wi * 7 + ti + SHIFT; if (i >= HH) i -= HH;
    int j = wj * 7 + tj + SHIFT; if (j >= WWp) j -= WWp;
    return b * L + i * WWp + j;
}

// Weights fp32->bf16 (196608 elems) + bias fragment table (16384 floats).
// biasd layout: [h][lane][mi][ni][r]; -1e30 for j>=49, 0 for i>=49.
__global__ __launch_bounds__(256) void wconv_kernel(
    const float* __restrict__ qkvw, const float* __restrict__ projw,
    const float* __restrict__ fc1w, const float* __restrict__ fc2w,
    const float* __restrict__ rpb, float* __restrict__ biasd,
    unsigned short* __restrict__ wb) {
    int i = blockIdx.x * 256 + threadIdx.x;
    float v;
    if (i < 49152)       v = qkvw[i];
    else if (i < 65536)  v = projw[i - 49152];
    else if (i < 131072) v = fc1w[i - 65536];
    else                 v = fc2w[i - 131072];
    wb[i] = f2bf(v);
    if (i < 16384) {
        int h = i >> 12, l = (i >> 6) & 63, f = i & 63;
        int mi = f >> 4, ni = (f >> 2) & 3, r = f & 3;
        int ii = mi * 16 + (l >> 4) * 4 + r;
        int jj = ni * 16 + (l & 15);
        float bv;
        if (jj >= 49)      bv = -1e30f;
        else if (ii >= 49) bv = 0.f;
        else {
            int yi = ii / 7, xi = ii - yi * 7, yj = jj / 7, xj = jj - yj * 7;
            bv = rpb[((yi - yj + 6) * 13 + (xi - xj + 6)) * NH + h];
        }
        biasd[i] = bv;
    }
}

// LayerNorm over C=128, fp32 in -> bf16 out. 1 wave/row, 4 rows/block.
__global__ __launch_bounds__(256) void ln_kernel(const float* __restrict__ in,
                                                 const float* __restrict__ g,
                                                 const float* __restrict__ bta,
                                                 unsigned short* __restrict__ out) {
    int row  = blockIdx.x * 4 + (threadIdx.x >> 6);
    int lane = threadIdx.x & 63;
    const float2 v = ((const float2*)(in + (long)row * C))[lane];
    float s  = v.x + v.y;
    float ss = v.x * v.x + v.y * v.y;
#pragma unroll
    for (int off = 32; off >= 1; off >>= 1) {
        s  += __shfl_xor(s, off);
        ss += __shfl_xor(ss, off);
    }
    float mu  = s * (1.0f / C);
    float var = ss * (1.0f / C) - mu * mu;
    float rs  = rsqrtf(var + 1e-5f);
    float2 gg = ((const float2*)g)[lane];
    float2 bb = ((const float2*)bta)[lane];
    ushort2 o;
    o.x = f2bf((v.x - mu) * rs * gg.x + bb.x);
    o.y = f2bf((v.y - mu) * rs * gg.y + bb.y);
    ((ushort2*)(out + (long)row * C))[lane] = o;
}

// Direct-fragment MFMA NT GEMM: no LDS staging, no barriers. out[m,n] =
// sum_k A[m,k]*W[n,k]. 128-row block, 4 waves (2x2), wave = 64x64 via 4x4
// frags of 16x16x32. A and B frags loaded straight from global (16 rows x
// one 64B line per frag -> full line utilization; weights are L2-resident).
// N-tiles looped INSIDE the block so A is fetched from HBM once.
// MODE 0: qkv (gather rows; q scaled; k [wh][49][32]; v^T [wh][32][64])
// MODE 1: proj (+ resid fp32 x; fused LN2: writes x2b AND h2n, scattered)
// MODE 2: fc1 (exact gelu; bf16 out)
// MODE 3: fc2 (+ resid bf16 x2b; fp32 out = d_out)
template<int MODE, int K, int NB, bool GATHER>
__global__ __launch_bounds__(256, 3) void gemm_direct(
    const unsigned short* __restrict__ A,
    const unsigned short* __restrict__ Wb,
    const float* __restrict__ bias,
    const float* __restrict__ residf,
    const unsigned short* __restrict__ residb,
    const float* __restrict__ g2, const float* __restrict__ b2,
    float* __restrict__ outf,
    unsigned short* __restrict__ outb,
    unsigned short* __restrict__ outb2)
{
    __shared__ float part[2][64][2][2];   // proj LN2 partials only
    const int tid = threadIdx.x;
    const int wid = tid >> 6, lane = tid & 63;
    const int g = lane >> 4, lr = lane & 15;
    const int wm = wid >> 1, wn = wid & 1;
    const int mbase = blockIdx.x * 128;
    long arow[4];
#pragma unroll
    for (int mi = 0; mi < 4; ++mi) {
        int gm = mbase + wm * 64 + mi * 16 + lr;
        arow[mi] = GATHER ? (long)win2orig(gm) : (long)gm;
    }

    for (int nb = 0; nb < NB; ++nb) {
        const int nbase = nb * 128;
        f32x4 acc[4][4] = {};
#pragma unroll
        for (int kb = 0; kb < K; kb += 128) {
#pragma unroll
            for (int kk = 0; kk < 4; ++kk) {
                bf16x8 af[4], bfr[4];
#pragma unroll
                for (int mi = 0; mi < 4; ++mi)
                    af[mi] = *(const bf16x8*)(A + arow[mi] * K + kb + kk * 32 + g * 8);
#pragma unroll
                for (int ni = 0; ni < 4; ++ni)
                    bfr[ni] = *(const bf16x8*)(Wb + (long)(nbase + wn * 64 + ni * 16 + lr) * K + kb + kk * 32 + g * 8);
#pragma unroll
                for (int mi = 0; mi < 4; ++mi)
#pragma unroll
                    for (int ni = 0; ni < 4; ++ni)
                        acc[mi][ni] = __builtin_amdgcn_mfma_f32_16x16x32_bf16(af[mi], bfr[ni], acc[mi][ni], 0, 0, 0);
            }
        }

        // Epilogue. D: col = lane&15 (=lr), row = g*4 + reg.
        if constexpr (MODE == 0) {
#pragma unroll
            for (int ni = 0; ni < 4; ++ni) {
                const int gn = nbase + wn * 64 + ni * 16 + lr;
                const float bi = bias[gn];
                const int part_ = gn >> 7, rem = gn & 127;
                const int hh = rem >> 5, dd = rem & 31;
#pragma unroll
                for (int mi = 0; mi < 4; ++mi)
#pragma unroll
                    for (int rg = 0; rg < 4; ++rg) {
                        const int gm = mbase + wm * 64 + mi * 16 + g * 4 + rg;
                        float val = acc[mi][ni][rg] + bi;
                        int w = gm / 49, t = gm - w * 49;
                        if (part_ == 2) {
                            outb[2L * M * 128 + (((long)(w * 4 + hh)) * 32 + dd) * 64 + t] = f2bf(val);
                        } else {
                            float vv = (part_ == 0) ? val * 0.17677669529663687f : val;
                            outb[(long)part_ * M * 128 + (((long)(w * 4 + hh)) * 49 + t) * 32 + dd] = f2bf(vv);
                        }
                    }
            }
        } else if constexpr (MODE == 1) {
            // x2 = x + (o@W + b); then LN2 in-register. Rows of this block
            // cover complete C=128 rows split across wn halves.
            int rrow[16];
#pragma unroll
            for (int mi = 0; mi < 4; ++mi)
#pragma unroll
                for (int rg = 0; rg < 4; ++rg)
                    rrow[mi * 4 + rg] = win2orig(mbase + wm * 64 + mi * 16 + g * 4 + rg);
#pragma unroll
            for (int mi = 0; mi < 4; ++mi)
#pragma unroll
                for (int rg = 0; rg < 4; ++rg) {
                    const long r = rrow[mi * 4 + rg];
#pragma unroll
                    for (int ni = 0; ni < 4; ++ni) {
                        const int gn = wn * 64 + ni * 16 + lr;
                        acc[mi][ni][rg] = residf[r * C + gn] + acc[mi][ni][rg] + bias[gn];
                    }
                }
            float sA[16], qA[16];
#pragma unroll
            for (int mi = 0; mi < 4; ++mi)
#pragma unroll
                for (int rg = 0; rg < 4; ++rg) {
                    float s = 0.f, q = 0.f;
#pragma unroll
                    for (int ni = 0; ni < 4; ++ni) {
                        float v = acc[mi][ni][rg];
                        s += v; q += v * v;
                    }
#pragma unroll
                    for (int off = 1; off <= 8; off <<= 1) {
                        s += __shfl_xor(s, off);
                        q += __shfl_xor(q, off);
                    }
                    sA[mi * 4 + rg] = s; qA[mi * 4 + rg] = q;
                }
            if (lr == 0) {
#pragma unroll
                for (int mi = 0; mi < 4; ++mi)
#pragma unroll
                    for (int rg = 0; rg < 4; ++rg) {
                        int r64 = mi * 16 + g * 4 + rg;
                        part[wm][r64][wn][0] = sA[mi * 4 + rg];
                        part[wm][r64][wn][1] = qA[mi * 4 + rg];
                    }
            }
            __syncthreads();
#pragma unroll
            for (int mi = 0; mi < 4; ++mi)
#pragma unroll
                for (int rg = 0; rg < 4; ++rg) {
                    const int idx = mi * 4 + rg;
                    const int r64 = mi * 16 + g * 4 + rg;
                    const float st = sA[idx] + part[wm][r64][wn ^ 1][0];
                    const float qt = qA[idx] + part[wm][r64][wn ^ 1][1];
                    const float mu = st * (1.0f / C);
                    const float var = qt * (1.0f / C) - mu * mu;
                    const float rs = rsqrtf(var + 1e-5f);
                    const long r = rrow[idx];
#pragma unroll
                    for (int ni = 0; ni < 4; ++ni) {
                        const int gn = wn * 64 + ni * 16 + lr;
                        const float xv = acc[mi][ni][rg];
                        outb2[r * C + gn] = f2bf(xv);
                        outb[r * C + gn]  = f2bf((xv - mu) * rs * g2[gn] + b2[gn]);
                    }
                }
        } else {
#pragma unroll
            for (int ni = 0; ni < 4; ++ni) {
                const int gn = nbase + wn * 64 + ni * 16 + lr;
                const float bi = bias[gn];
#pragma unroll
                for (int mi = 0; mi < 4; ++mi)
#pragma unroll
                    for (int rg = 0; rg < 4; ++rg) {
                        const int gm = mbase + wm * 64 + mi * 16 + g * 4 + rg;
                        float val = acc[mi][ni][rg] + bi;
                        if constexpr (MODE == 2) {
                            float ge = 0.5f * val * (1.0f + erff(val * 0.70710678118654752f));
                            outb[(long)gm * HID + gn] = f2bf(ge);
                        } else {
                            outf[(long)gm * C + gn] = bf2f(residb[(long)gm * C + gn]) + val;
                        }
                    }
            }
        }
    }
}

// MFMA attention: 1 block/window, 1 wave/head (unchanged from round 3).
__global__ __launch_bounds__(256) void attn_mfma(
    const unsigned short* __restrict__ qb,   // [wh][49][32], pre-scaled
    const unsigned short* __restrict__ kb,   // [wh][49][32]
    const unsigned short* __restrict__ vtb,  // [wh][32][64] (V^T)
    const float* __restrict__ biasd,         // [h][lane][mi][ni][r]
    unsigned short* __restrict__ ob)         // [w*49+t][128]
{
    __shared__ __align__(16) char Pt[4][8192];
    const int tid  = threadIdx.x;
    const int h    = tid >> 6;
    const int lane = tid & 63;
    const int g    = lane >> 4, lr = lane & 15;
    const int w    = blockIdx.x;
    const long wh  = (long)(w * 4 + h);
    const unsigned short* qp = qb  + wh * (49 * 32);
    const unsigned short* kp = kb  + wh * (49 * 32);
    const unsigned short* vp = vtb + wh * (32 * 64);

    bf16x8 qf[4], kf[4];
#pragma unroll
    for (int mi = 0; mi < 4; ++mi) {
        qf[mi] = *(const bf16x8*)(qp + (mi * 16 + lr) * 32 + g * 8);
        kf[mi] = *(const bf16x8*)(kp + (mi * 16 + lr) * 32 + g * 8);
    }
    f32x4 acc[4][4] = {};
#pragma unroll
    for (int mi = 0; mi < 4; ++mi)
#pragma unroll
        for (int ni = 0; ni < 4; ++ni)
            acc[mi][ni] = __builtin_amdgcn_mfma_f32_16x16x32_bf16(qf[mi], kf[ni], acc[mi][ni], 0, 0, 0);

    const float* bp = biasd + (h * 64 + lane) * 64;
    char* ptw = &Pt[h][0];
#pragma unroll
    for (int mi = 0; mi < 4; ++mi) {
#pragma unroll
        for (int ni = 0; ni < 4; ++ni)
            acc[mi][ni] += *(const f32x4*)(bp + mi * 16 + ni * 4);
#pragma unroll
        for (int c = 0; c < 4; ++c)
            acc[mi][3][c] = (lr == 0) ? acc[mi][3][c] : -1e30f;
        f32x4 mx;
#pragma unroll
        for (int c = 0; c < 4; ++c)
            mx[c] = fmaxf(fmaxf(acc[mi][0][c], acc[mi][1][c]), fmaxf(acc[mi][2][c], acc[mi][3][c]));
#pragma unroll
        for (int off = 1; off <= 8; off <<= 1)
#pragma unroll
            for (int c = 0; c < 4; ++c)
                mx[c] = fmaxf(mx[c], __shfl_xor(mx[c], off));
        f32x4 sum = {};
#pragma unroll
        for (int ni = 0; ni < 4; ++ni)
#pragma unroll
            for (int c = 0; c < 4; ++c) {
                float e = __expf(acc[mi][ni][c] - mx[c]);
                acc[mi][ni][c] = e;
                sum[c] += e;
            }
#pragma unroll
        for (int off = 1; off <= 8; off <<= 1)
#pragma unroll
            for (int c = 0; c < 4; ++c)
                sum[c] += __shfl_xor(sum[c], off);
        f32x4 inv;
#pragma unroll
        for (int c = 0; c < 4; ++c)
            inv[c] = __builtin_amdgcn_rcpf(sum[c]);
#pragma unroll
        for (int ni = 0; ni < 4; ++ni) {
            ushort4 pw;
            pw.x = f2bf(acc[mi][ni][0] * inv[0]);
            pw.y = f2bf(acc[mi][ni][1] * inv[1]);
            pw.z = f2bf(acc[mi][ni][2] * inv[2]);
            pw.w = f2bf(acc[mi][ni][3] * inv[3]);
            int jb  = ni * 4 + (lr >> 2);
            int tix = (((jb >> 3) * 2 + (jb & 1)) * 4 + mi) * 4 + ((jb >> 1) & 3);
            *(ushort4*)(ptw + tix * 128 + (lr & 3) * 32 + g * 8) = pw;
        }
    }
    __syncthreads();

    bf16x8 vf[2][2];
#pragma unroll
    for (int md = 0; md < 2; ++md) {
#pragma unroll
        for (int kk = 0; kk < 2; ++kk)
            vf[md][kk] = *(const bf16x8*)(vp + (md * 16 + lr) * 64 + kk * 32 + g * 8);
#pragma unroll
        for (int e = 0; e < 8; ++e)
            if (g * 8 + e > 16) vf[md][1][e] = (__bf16)0.0f;
    }

    const unsigned pbase = lds_addr(&Pt[h][0]);
    f32x4 accO[2][4] = {};
#pragma unroll
    for (int kk = 0; kk < 2; ++kk) {
        long tt[4][2];
#pragma unroll
        for (int ni = 0; ni < 4; ++ni)
#pragma unroll
            for (int s = 0; s < 2; ++s) {
                unsigned a = pbase + ((((kk * 2 + s) * 4 + ni) * 4 + g) * 128) + lr * 2;
                asm volatile("ds_read_b64_tr_b16 %0, %1" : "=v"(tt[ni][s]) : "v"(a));
            }
        asm volatile("s_waitcnt lgkmcnt(0)" ::: "memory");
        __builtin_amdgcn_sched_barrier(0);
#pragma unroll
        for (int ni = 0; ni < 4; ++ni) {
            union { int4 i4; bf16x8 v; } u;
            u.i4 = make_int4((int)tt[ni][0], (int)(tt[ni][0] >> 32),
                             (int)tt[ni][1], (int)(tt[ni][1] >> 32));
#pragma unroll
            for (int md = 0; md < 2; ++md)
                accO[md][ni] = __builtin_amdgcn_mfma_f32_16x16x32_bf16(vf[md][kk], u.v, accO[md][ni], 0, 0, 0);
        }
    }
#pragma unroll
    for (int ni = 0; ni < 4; ++ni) {
        int i = ni * 16 + lr;
        if (i < 49) {
#pragma unroll
            for (int md = 0; md < 2; ++md) {
                ushort4 ov;
                ov.x = f2bf(accO[md][ni][0]);
                ov.y = f2bf(accO[md][ni][1]);
                ov.z = f2bf(accO[md][ni][2]);
                ov.w = f2bf(accO[md][ni][3]);
                *(ushort4*)(ob + ((long)(w * 49 + i)) * 128 + h * 32 + md * 16 + g * 4) = ov;
            }
        }
    }
}

extern "C" void kernel_launch(void* const* d_in, const int* in_sizes, int n_in,
                              void* d_out, int out_size, void* d_ws, size_t ws_size,
                              hipStream_t stream) {
    const float* x      = (const float*)d_in[0];
    const float* n1g    = (const float*)d_in[1];
    const float* n1b    = (const float*)d_in[2];
    const float* qkv_w  = (const float*)d_in[3];
    const float* qkv_b  = (const float*)d_in[4];
    const float* proj_w = (const float*)d_in[5];
    const float* proj_b = (const float*)d_in[6];
    const float* rpb    = (const float*)d_in[7];
    const float* n2g    = (const float*)d_in[8];
    const float* n2b    = (const float*)d_in[9];
    const float* fc1_w  = (const float*)d_in[10];
    const float* fc1_b  = (const float*)d_in[11];
    const float* fc2_w  = (const float*)d_in[12];
    const float* fc2_b  = (const float*)d_in[13];
    float* out = (float*)d_out;

    // Workspace (~324 MB):
    //  [0,SZ)             hnorm -> o -> h2[0:..]
    //  [SZ,3SZ+VT)        q | k | v^T
    //  [3SZ+VT, 4SZ+VT)   x2b bf16
    //  [4SZ+VT, 5SZ+VT)   h2n
    //  [5SZ+VT, ..)       weights bf16 (384KB) + biasd (64KB)
    //  h2 = [0,4SZ)  (regions dead by fc1 time)
    char* ws = (char*)d_ws;
    const size_t SZ = (size_t)M * C * 2;                    // 51,380,224
    const size_t VT = (size_t)NWIN * NH * 32 * 64 * 2;      // 67,108,864
    unsigned short* hnorm  = (unsigned short*)(ws);
    unsigned short* qkvbuf = (unsigned short*)(ws + SZ);
    unsigned short* o      = hnorm;
    unsigned short* x2b    = (unsigned short*)(ws + 3 * SZ + VT);
    unsigned short* h2n    = (unsigned short*)(ws + 4 * SZ + VT);
    unsigned short* h2     = (unsigned short*)(ws);
    unsigned short* wb     = (unsigned short*)(ws + 5 * SZ + VT);
    float* biasd           = (float*)(ws + 5 * SZ + VT + 393216);
    unsigned short* wqkv = wb, *wproj = wb + 49152, *wfc1 = wb + 65536, *wfc2 = wb + 131072;

    wconv_kernel<<<768, 256, 0, stream>>>(qkv_w, proj_w, fc1_w, fc2_w, rpb, biasd, wb);
    ln_kernel<<<M / 4, 256, 0, stream>>>(x, n1g, n1b, hnorm);
    gemm_direct<0, 128, 3, true ><<<M / 128, 256, 0, stream>>>(hnorm, wqkv, qkv_b, nullptr, nullptr, nullptr, nullptr, nullptr, qkvbuf, nullptr);
    attn_mfma<<<NWIN, 256, 0, stream>>>(qkvbuf, qkvbuf + (size_t)M * 128, qkvbuf + 2 * (size_t)M * 128, biasd, o);
    gemm_direct<1, 128, 1, false><<<M / 128, 256, 0, stream>>>(o, wproj, proj_b, x, nullptr, n2g, n2b, nullptr, h2n, x2b);
    gemm_direct<2, 128, 4, false><<<M / 128, 256, 0, stream>>>(h2n, wfc1, fc1_b, nullptr, nullptr, nullptr, nullptr, nullptr, h2, nullptr);
    gemm_direct<3, 512, 1, false><<<M / 128, 256, 0, stream>>>(h2, wfc2, fc2_b, nullptr, x2b, nullptr, nullptr, out, nullptr, nullptr);
}

// Round 5
// 595.710 us; speedup vs baseline: 1.6668x; 1.6668x over previous
//
#include <hip/hip_runtime.h>
#include <stdint.h>

// Swin block: B=64, H=W=56, C=128, HID=512, WS=7, NH=4, SHIFT=3
static constexpr int Bz   = 64;
static constexpr int HH   = 56, WWp = 56;
static constexpr int C    = 128, HID = 512;
static constexpr int L    = HH * WWp;        // 3136
static constexpr int M    = Bz * L;          // 200704
static constexpr int NWIN = Bz * 64;         // 4096 windows
static constexpr int NH   = 4;
static constexpr int SHIFT = 3;

typedef __bf16 bf16x8 __attribute__((ext_vector_type(8)));
typedef float  f32x4  __attribute__((ext_vector_type(4)));

__device__ __forceinline__ float bf2f(unsigned short u) {
    return __uint_as_float(((unsigned int)u) << 16);
}
__device__ __forceinline__ unsigned short f2bf(float f) {
    unsigned int u = __float_as_uint(f);
    return (unsigned short)((u + 0x7FFFu + ((u >> 16) & 1u)) >> 16);
}
__device__ __forceinline__ unsigned lds_addr(const void* p) {
    return (unsigned)(size_t)(__attribute__((address_space(3))) const char*)p;
}

// window-order row m -> original (b,l) row: roll(-SHIFT) + 7x7 partition.
__device__ __forceinline__ int win2orig(int m) {
    int w = m / 49, t = m - w * 49;
    int b = w >> 6, wi = (w >> 3) & 7, wj = w & 7;
    int ti = t / 7, tj = t - ti * 7;
    int i = wi * 7 + ti + SHIFT; if (i >= HH) i -= HH;
    int j = wj * 7 + tj + SHIFT; if (j >= WWp) j -= WWp;
    return b * L + i * WWp + j;
}

__device__ __forceinline__ void async_copy16(void* ldsdst, const void* gsrc) {
    __builtin_amdgcn_global_load_lds(
        (const __attribute__((address_space(1))) unsigned int*)gsrc,
        (__attribute__((address_space(3))) unsigned int*)ldsdst,
        16, 0, 0);
}

// Weights fp32->bf16 (196608 elems) + bias fragment table (16384 floats).
// biasd layout: [h][lane][mi][ni][r]; -1e30 for j>=49, 0 for i>=49.
__global__ __launch_bounds__(256) void wconv_kernel(
    const float* __restrict__ qkvw, const float* __restrict__ projw,
    const float* __restrict__ fc1w, const float* __restrict__ fc2w,
    const float* __restrict__ rpb, float* __restrict__ biasd,
    unsigned short* __restrict__ wb) {
    int i = blockIdx.x * 256 + threadIdx.x;
    float v;
    if (i < 49152)       v = qkvw[i];
    else if (i < 65536)  v = projw[i - 49152];
    else if (i < 131072) v = fc1w[i - 65536];
    else                 v = fc2w[i - 131072];
    wb[i] = f2bf(v);
    if (i < 16384) {
        int h = i >> 12, l = (i >> 6) & 63, f = i & 63;
        int mi = f >> 4, ni = (f >> 2) & 3, r = f & 3;
        int ii = mi * 16 + (l >> 4) * 4 + r;
        int jj = ni * 16 + (l & 15);
        float bv;
        if (jj >= 49)      bv = -1e30f;
        else if (ii >= 49) bv = 0.f;
        else {
            int yi = ii / 7, xi = ii - yi * 7, yj = jj / 7, xj = jj - yj * 7;
            bv = rpb[((yi - yj + 6) * 13 + (xi - xj + 6)) * NH + h];
        }
        biasd[i] = bv;
    }
}

// LayerNorm over C=128, fp32 in -> bf16 out. 1 wave/row, 4 rows/block.
__global__ __launch_bounds__(256) void ln_kernel(const float* __restrict__ in,
                                                 const float* __restrict__ g,
                                                 const float* __restrict__ bta,
                                                 unsigned short* __restrict__ out) {
    int row  = blockIdx.x * 4 + (threadIdx.x >> 6);
    int lane = threadIdx.x & 63;
    const float2 v = ((const float2*)(in + (long)row * C))[lane];
    float s  = v.x + v.y;
    float ss = v.x * v.x + v.y * v.y;
#pragma unroll
    for (int off = 32; off >= 1; off >>= 1) {
        s  += __shfl_xor(s, off);
        ss += __shfl_xor(ss, off);
    }
    float mu  = s * (1.0f / C);
    float var = ss * (1.0f / C) - mu * mu;
    float rs  = rsqrtf(var + 1e-5f);
    float2 gg = ((const float2*)g)[lane];
    float2 bb = ((const float2*)bta)[lane];
    ushort2 o;
    o.x = f2bf((v.x - mu) * rs * gg.x + bb.x);
    o.y = f2bf((v.y - mu) * rs * gg.y + bb.y);
    ((ushort2*)(out + (long)row * C))[lane] = o;
}

// Pipelined LDS-staged MFMA NT GEMM. out[m,n] = sum_k A[m,k]*W[n,k].
// 128-row block, 4 waves (2x2), wave = 64x64 via 4x4 frags of 16x16x32.
// N-tiles loop INSIDE the block (A staged once for K<=128). K processed in
// 64-wide halves, B (and A for K=512) double-buffered: next half's
// global_load_lds issued BEFORE current half's ds_read+MFMA, one
// __syncthreads per half (stage latency hides under 32 MFMAs/wave).
// MODE 0: qkv (gather rows; q scaled; k [wh][49][32]; v^T [wh][32][64])
// MODE 1: proj (+ resid fp32 x; fused LN2: writes x2b AND h2n, scattered)
// MODE 2: fc1 (exact gelu; bf16 out)
// MODE 3: fc2 (+ resid bf16 x2b; fp32 out = d_out)
template<int MODE, int K, int NB, bool GATHER>
__global__ __launch_bounds__(256) void gemm_pipe(
    const unsigned short* __restrict__ A,
    const unsigned short* __restrict__ Wb,
    const float* __restrict__ bias,
    const float* __restrict__ residf,
    const unsigned short* __restrict__ residb,
    const float* __restrict__ g2, const float* __restrict__ b2,
    float* __restrict__ outf,
    unsigned short* __restrict__ outb,
    unsigned short* __restrict__ outb2)
{
    constexpr int KH = K / 64;          // K-halves
    constexpr bool BIGK = (K > 128);
    __shared__ char lds[65536];
    __shared__ float lnpart[2][64][2][2];
    char* ldsA = lds;                   // BIGK: dbuf 2x16KB ; else full 32KB
    char* ldsB = lds + 32768;           // dbuf 2x16KB
    const int tid = threadIdx.x;
    const int wid = tid >> 6, lane = tid & 63;
    const int g = lane >> 4, lr = lane & 15;
    const int wm = wid >> 1, wn = wid & 1;
    const int mbase = blockIdx.x * 128;

    auto stageAfull = [&]() {
#pragma unroll
        for (int i = 0; i < 8; ++i) {
            const int c = i * 4 + wid;
            const int r = (c << 2) + (lane >> 4);
            const int s = (lane & 15) ^ (r & 15);
            long arow = GATHER ? (long)win2orig(mbase + r) : (long)(mbase + r);
            async_copy16(ldsA + c * 1024, (const char*)A + arow * (K * 2) + s * 16);
        }
    };
    auto stageAhalf = [&](int buf, int kh) {
#pragma unroll
        for (int i = 0; i < 4; ++i) {
            const int c = i * 4 + wid;
            const int r = (c << 3) + (lane >> 3);
            const int s = (lane & 7) ^ (r & 7);
            async_copy16(ldsA + buf * 16384 + c * 1024,
                         (const char*)A + (long)(mbase + r) * (K * 2) + kh * 128 + s * 16);
        }
    };
    auto stageBhalf = [&](int buf, int nb, int kh) {
#pragma unroll
        for (int i = 0; i < 4; ++i) {
            const int c = i * 4 + wid;
            const int r = (c << 3) + (lane >> 3);
            const int s = (lane & 7) ^ (r & 7);
            async_copy16(ldsB + buf * 16384 + c * 1024,
                         (const char*)Wb + (long)(nb * 128 + r) * (K * 2) + kh * 128 + s * 16);
        }
    };

    if constexpr (!BIGK) stageAfull(); else stageAhalf(0, 0);
    stageBhalf(0, 0, 0);
    __syncthreads();
    int cur = 0;

    for (int nb = 0; nb < NB; ++nb) {
        const int nbase = nb * 128;
        f32x4 acc[4][4] = {};
        for (int kh = 0; kh < KH; ++kh) {
            const bool last = (nb == NB - 1) && (kh == KH - 1);
            if (!last) {
                const int nnb = (kh == KH - 1) ? nb + 1 : nb;
                const int nkh = (kh == KH - 1) ? 0 : kh + 1;
                if constexpr (BIGK) stageAhalf(cur ^ 1, nkh);
                stageBhalf(cur ^ 1, nnb, nkh);
            }
#pragma unroll
            for (int kkh = 0; kkh < 2; ++kkh) {
                bf16x8 af[4], bfr[4];
#pragma unroll
                for (int mi = 0; mi < 4; ++mi) {
                    const int ra = wm * 64 + mi * 16 + lr;
                    if constexpr (BIGK) {
                        af[mi] = *(const bf16x8*)(ldsA + cur * 16384 + ra * 128 + (((kkh * 4 + g) ^ (ra & 7)) * 16));
                    } else {
                        const int kk = kh * 2 + kkh;
                        af[mi] = *(const bf16x8*)(ldsA + ra * 256 + (((kk * 4 + g) ^ (ra & 15)) * 16));
                    }
                }
#pragma unroll
                for (int ni = 0; ni < 4; ++ni) {
                    const int rb = wn * 64 + ni * 16 + lr;
                    bfr[ni] = *(const bf16x8*)(ldsB + cur * 16384 + rb * 128 + (((kkh * 4 + g) ^ (rb & 7)) * 16));
                }
#pragma unroll
                for (int mi = 0; mi < 4; ++mi)
#pragma unroll
                    for (int ni = 0; ni < 4; ++ni)
                        acc[mi][ni] = __builtin_amdgcn_mfma_f32_16x16x32_bf16(af[mi], bfr[ni], acc[mi][ni], 0, 0, 0);
            }
            if (!last) { __syncthreads(); cur ^= 1; }
        }

        // Epilogue for this nb. D: col = lane&15 (=lr), row = g*4 + reg.
        if constexpr (MODE == 0) {
#pragma unroll
            for (int ni = 0; ni < 4; ++ni) {
                const int gn = nbase + wn * 64 + ni * 16 + lr;
                const float bi = bias[gn];
                const int prt = gn >> 7, rem = gn & 127;
                const int hh = rem >> 5, dd = rem & 31;
#pragma unroll
                for (int mi = 0; mi < 4; ++mi)
#pragma unroll
                    for (int rg = 0; rg < 4; ++rg) {
                        const int gm = mbase + wm * 64 + mi * 16 + g * 4 + rg;
                        float val = acc[mi][ni][rg] + bi;
                        int w = gm / 49, t = gm - w * 49;
                        if (prt == 2) {
                            outb[2L * M * 128 + (((long)(w * 4 + hh)) * 32 + dd) * 64 + t] = f2bf(val);
                        } else {
                            float vv = (prt == 0) ? val * 0.17677669529663687f : val;
                            outb[(long)prt * M * 128 + (((long)(w * 4 + hh)) * 49 + t) * 32 + dd] = f2bf(vv);
                        }
                    }
            }
        } else if constexpr (MODE == 1) {
            // x2 = x + (o@W + b); then LN2 in-register (NB==1, full C rows).
            int rrow[16];
#pragma unroll
            for (int mi = 0; mi < 4; ++mi)
#pragma unroll
                for (int rg = 0; rg < 4; ++rg)
                    rrow[mi * 4 + rg] = win2orig(mbase + wm * 64 + mi * 16 + g * 4 + rg);
#pragma unroll
            for (int mi = 0; mi < 4; ++mi)
#pragma unroll
                for (int rg = 0; rg < 4; ++rg) {
                    const long r = rrow[mi * 4 + rg];
#pragma unroll
                    for (int ni = 0; ni < 4; ++ni) {
                        const int gn = wn * 64 + ni * 16 + lr;
                        acc[mi][ni][rg] = residf[r * C + gn] + acc[mi][ni][rg] + bias[gn];
                    }
                }
            float sA[16], qA[16];
#pragma unroll
            for (int mi = 0; mi < 4; ++mi)
#pragma unroll
                for (int rg = 0; rg < 4; ++rg) {
                    float s = 0.f, q = 0.f;
#pragma unroll
                    for (int ni = 0; ni < 4; ++ni) {
                        float v = acc[mi][ni][rg];
                        s += v; q += v * v;
                    }
#pragma unroll
                    for (int off = 1; off <= 8; off <<= 1) {
                        s += __shfl_xor(s, off);
                        q += __shfl_xor(q, off);
                    }
                    sA[mi * 4 + rg] = s; qA[mi * 4 + rg] = q;
                }
            __syncthreads();
            if (lr == 0) {
#pragma unroll
                for (int mi = 0; mi < 4; ++mi)
#pragma unroll
                    for (int rg = 0; rg < 4; ++rg) {
                        int r64 = mi * 16 + g * 4 + rg;
                        lnpart[wm][r64][wn][0] = sA[mi * 4 + rg];
                        lnpart[wm][r64][wn][1] = qA[mi * 4 + rg];
                    }
            }
            __syncthreads();
#pragma unroll
            for (int mi = 0; mi < 4; ++mi)
#pragma unroll
                for (int rg = 0; rg < 4; ++rg) {
                    const int idx = mi * 4 + rg;
                    const int r64 = mi * 16 + g * 4 + rg;
                    const float st = sA[idx] + lnpart[wm][r64][wn ^ 1][0];
                    const float qt = qA[idx] + lnpart[wm][r64][wn ^ 1][1];
                    const float mu = st * (1.0f / C);
                    const float var = qt * (1.0f / C) - mu * mu;
                    const float rs = rsqrtf(var + 1e-5f);
                    const long r = rrow[idx];
#pragma unroll
                    for (int ni = 0; ni < 4; ++ni) {
                        const int gn = wn * 64 + ni * 16 + lr;
                        const float xv = acc[mi][ni][rg];
                        outb2[r * C + gn] = f2bf(xv);
                        outb[r * C + gn]  = f2bf((xv - mu) * rs * g2[gn] + b2[gn]);
                    }
                }
        } else {
#pragma unroll
            for (int ni = 0; ni < 4; ++ni) {
                const int gn = nbase + wn * 64 + ni * 16 + lr;
                const float bi = bias[gn];
#pragma unroll
                for (int mi = 0; mi < 4; ++mi)
#pragma unroll
                    for (int rg = 0; rg < 4; ++rg) {
                        const int gm = mbase + wm * 64 + mi * 16 + g * 4 + rg;
                        float val = acc[mi][ni][rg] + bi;
                        if constexpr (MODE == 2) {
                            float ge = 0.5f * val * (1.0f + erff(val * 0.70710678118654752f));
                            outb[(long)gm * HID + gn] = f2bf(ge);
                        } else {
                            outf[(long)gm * C + gn] = bf2f(residb[(long)gm * C + gn]) + val;
                        }
                    }
            }
        }
    }
}

// MFMA attention: 1 block/window, 1 wave/head (unchanged, proven round 3).
__global__ __launch_bounds__(256) void attn_mfma(
    const unsigned short* __restrict__ qb,   // [wh][49][32], pre-scaled
    const unsigned short* __restrict__ kb,   // [wh][49][32]
    const unsigned short* __restrict__ vtb,  // [wh][32][64] (V^T)
    const float* __restrict__ biasd,         // [h][lane][mi][ni][r]
    unsigned short* __restrict__ ob)         // [w*49+t][128]
{
    __shared__ __align__(16) char Pt[4][8192];
    const int tid  = threadIdx.x;
    const int h    = tid >> 6;
    const int lane = tid & 63;
    const int g    = lane >> 4, lr = lane & 15;
    const int w    = blockIdx.x;
    const long wh  = (long)(w * 4 + h);
    const unsigned short* qp = qb  + wh * (49 * 32);
    const unsigned short* kp = kb  + wh * (49 * 32);
    const unsigned short* vp = vtb + wh * (32 * 64);

    bf16x8 qf[4], kf[4];
#pragma unroll
    for (int mi = 0; mi < 4; ++mi) {
        qf[mi] = *(const bf16x8*)(qp + (mi * 16 + lr) * 32 + g * 8);
        kf[mi] = *(const bf16x8*)(kp + (mi * 16 + lr) * 32 + g * 8);
    }
    f32x4 acc[4][4] = {};
#pragma unroll
    for (int mi = 0; mi < 4; ++mi)
#pragma unroll
        for (int ni = 0; ni < 4; ++ni)
            acc[mi][ni] = __builtin_amdgcn_mfma_f32_16x16x32_bf16(qf[mi], kf[ni], acc[mi][ni], 0, 0, 0);

    const float* bp = biasd + (h * 64 + lane) * 64;
    char* ptw = &Pt[h][0];
#pragma unroll
    for (int mi = 0; mi < 4; ++mi) {
#pragma unroll
        for (int ni = 0; ni < 4; ++ni)
            acc[mi][ni] += *(const f32x4*)(bp + mi * 16 + ni * 4);
#pragma unroll
        for (int c = 0; c < 4; ++c)
            acc[mi][3][c] = (lr == 0) ? acc[mi][3][c] : -1e30f;
        f32x4 mx;
#pragma unroll
        for (int c = 0; c < 4; ++c)
            mx[c] = fmaxf(fmaxf(acc[mi][0][c], acc[mi][1][c]), fmaxf(acc[mi][2][c], acc[mi][3][c]));
#pragma unroll
        for (int off = 1; off <= 8; off <<= 1)
#pragma unroll
            for (int c = 0; c < 4; ++c)
                mx[c] = fmaxf(mx[c], __shfl_xor(mx[c], off));
        f32x4 sum = {};
#pragma unroll
        for (int ni = 0; ni < 4; ++ni)
#pragma unroll
            for (int c = 0; c < 4; ++c) {
                float e = __expf(acc[mi][ni][c] - mx[c]);
                acc[mi][ni][c] = e;
                sum[c] += e;
            }
#pragma unroll
        for (int off = 1; off <= 8; off <<= 1)
#pragma unroll
            for (int c = 0; c < 4; ++c)
                sum[c] += __shfl_xor(sum[c], off);
        f32x4 inv;
#pragma unroll
        for (int c = 0; c < 4; ++c)
            inv[c] = __builtin_amdgcn_rcpf(sum[c]);
#pragma unroll
        for (int ni = 0; ni < 4; ++ni) {
            ushort4 pw;
            pw.x = f2bf(acc[mi][ni][0] * inv[0]);
            pw.y = f2bf(acc[mi][ni][1] * inv[1]);
            pw.z = f2bf(acc[mi][ni][2] * inv[2]);
            pw.w = f2bf(acc[mi][ni][3] * inv[3]);
            int jb  = ni * 4 + (lr >> 2);
            int tix = (((jb >> 3) * 2 + (jb & 1)) * 4 + mi) * 4 + ((jb >> 1) & 3);
            *(ushort4*)(ptw + tix * 128 + (lr & 3) * 32 + g * 8) = pw;
        }
    }
    __syncthreads();

    bf16x8 vf[2][2];
#pragma unroll
    for (int md = 0; md < 2; ++md) {
#pragma unroll
        for (int kk = 0; kk < 2; ++kk)
            vf[md][kk] = *(const bf16x8*)(vp + (md * 16 + lr) * 64 + kk * 32 + g * 8);
#pragma unroll
        for (int e = 0; e < 8; ++e)
            if (g * 8 + e > 16) vf[md][1][e] = (__bf16)0.0f;
    }

    const unsigned pbase = lds_addr(&Pt[h][0]);
    f32x4 accO[2][4] = {};
#pragma unroll
    for (int kk = 0; kk < 2; ++kk) {
        long tt[4][2];
#pragma unroll
        for (int ni = 0; ni < 4; ++ni)
#pragma unroll
            for (int s = 0; s < 2; ++s) {
                unsigned a = pbase + ((((kk * 2 + s) * 4 + ni) * 4 + g) * 128) + lr * 2;
                asm volatile("ds_read_b64_tr_b16 %0, %1" : "=v"(tt[ni][s]) : "v"(a));
            }
        asm volatile("s_waitcnt lgkmcnt(0)" ::: "memory");
        __builtin_amdgcn_sched_barrier(0);
#pragma unroll
        for (int ni = 0; ni < 4; ++ni) {
            union { int4 i4; bf16x8 v; } u;
            u.i4 = make_int4((int)tt[ni][0], (int)(tt[ni][0] >> 32),
                             (int)tt[ni][1], (int)(tt[ni][1] >> 32));
#pragma unroll
            for (int md = 0; md < 2; ++md)
                accO[md][ni] = __builtin_amdgcn_mfma_f32_16x16x32_bf16(vf[md][kk], u.v, accO[md][ni], 0, 0, 0);
        }
    }
#pragma unroll
    for (int ni = 0; ni < 4; ++ni) {
        int i = ni * 16 + lr;
        if (i < 49) {
#pragma unroll
            for (int md = 0; md < 2; ++md) {
                ushort4 ov;
                ov.x = f2bf(accO[md][ni][0]);
                ov.y = f2bf(accO[md][ni][1]);
                ov.z = f2bf(accO[md][ni][2]);
                ov.w = f2bf(accO[md][ni][3]);
                *(ushort4*)(ob + ((long)(w * 49 + i)) * 128 + h * 32 + md * 16 + g * 4) = ov;
            }
        }
    }
}

extern "C" void kernel_launch(void* const* d_in, const int* in_sizes, int n_in,
                              void* d_out, int out_size, void* d_ws, size_t ws_size,
                              hipStream_t stream) {
    const float* x      = (const float*)d_in[0];
    const float* n1g    = (const float*)d_in[1];
    const float* n1b    = (const float*)d_in[2];
    const float* qkv_w  = (const float*)d_in[3];
    const float* qkv_b  = (const float*)d_in[4];
    const float* proj_w = (const float*)d_in[5];
    const float* proj_b = (const float*)d_in[6];
    const float* rpb    = (const float*)d_in[7];
    const float* n2g    = (const float*)d_in[8];
    const float* n2b    = (const float*)d_in[9];
    const float* fc1_w  = (const float*)d_in[10];
    const float* fc1_b  = (const float*)d_in[11];
    const float* fc2_w  = (const float*)d_in[12];
    const float* fc2_b  = (const float*)d_in[13];
    float* out = (float*)d_out;

    // Workspace (~324 MB):
    //  [0,SZ)             hnorm -> o -> h2[0:..]
    //  [SZ,3SZ+VT)        q | k | v^T
    //  [3SZ+VT, 4SZ+VT)   x2b bf16
    //  [4SZ+VT, 5SZ+VT)   h2n
    //  [5SZ+VT, ..)       weights bf16 (384KB) + biasd (64KB)
    //  h2 = [0,4SZ)  (regions dead by fc1 time)
    char* ws = (char*)d_ws;
    const size_t SZ = (size_t)M * C * 2;                    // 51,380,224
    const size_t VT = (size_t)NWIN * NH * 32 * 64 * 2;      // 67,108,864
    unsigned short* hnorm  = (unsigned short*)(ws);
    unsigned short* qkvbuf = (unsigned short*)(ws + SZ);
    unsigned short* o      = hnorm;
    unsigned short* x2b    = (unsigned short*)(ws + 3 * SZ + VT);
    unsigned short* h2n    = (unsigned short*)(ws + 4 * SZ + VT);
    unsigned short* h2     = (unsigned short*)(ws);
    unsigned short* wb     = (unsigned short*)(ws + 5 * SZ + VT);
    float* biasd           = (float*)(ws + 5 * SZ + VT + 393216);
    unsigned short* wqkv = wb, *wproj = wb + 49152, *wfc1 = wb + 65536, *wfc2 = wb + 131072;

    wconv_kernel<<<768, 256, 0, stream>>>(qkv_w, proj_w, fc1_w, fc2_w, rpb, biasd, wb);
    ln_kernel<<<M / 4, 256, 0, stream>>>(x, n1g, n1b, hnorm);
    gemm_pipe<0, 128, 3, true ><<<M / 128, 256, 0, stream>>>(hnorm, wqkv, qkv_b, nullptr, nullptr, nullptr, nullptr, nullptr, qkvbuf, nullptr);
    attn_mfma<<<NWIN, 256, 0, stream>>>(qkvbuf, qkvbuf + (size_t)M * 128, qkvbuf + 2 * (size_t)M * 128, biasd, o);
    gemm_pipe<1, 128, 1, false><<<M / 128, 256, 0, stream>>>(o, wproj, proj_b, x, nullptr, n2g, n2b, nullptr, h2n, x2b);
    gemm_pipe<2, 128, 4, false><<<M / 128, 256, 0, stream>>>(h2n, wfc1, fc1_b, nullptr, nullptr, nullptr, nullptr, nullptr, h2, nullptr);
    gemm_pipe<3, 512, 1, false><<<M / 128, 256, 0, stream>>>(h2, wfc2, fc2_b, nullptr, x2b, nullptr, nullptr, out, nullptr, nullptr);
}

// Round 6
// 453.999 us; speedup vs baseline: 2.1871x; 1.3121x over previous
//
#include <hip/hip_runtime.h>
#include <stdint.h>

// Swin block: B=64, H=W=56, C=128, HID=512, WS=7, NH=4, SHIFT=3
static constexpr int Bz   = 64;
static constexpr int HH   = 56, WWp = 56;
static constexpr int C    = 128, HID = 512;
static constexpr int L    = HH * WWp;        // 3136
static constexpr int M    = Bz * L;          // 200704
static constexpr int NWIN = Bz * 64;         // 4096 windows
static constexpr int NH   = 4;
static constexpr int SHIFT = 3;

typedef __bf16 bf16x8 __attribute__((ext_vector_type(8)));
typedef float  f32x4  __attribute__((ext_vector_type(4)));

__device__ __forceinline__ float bf2f(unsigned short u) {
    return __uint_as_float(((unsigned int)u) << 16);
}
__device__ __forceinline__ unsigned short f2bf(float f) {
    unsigned int u = __float_as_uint(f);
    return (unsigned short)((u + 0x7FFFu + ((u >> 16) & 1u)) >> 16);
}
__device__ __forceinline__ unsigned lds_addr(const void* p) {
    return (unsigned)(size_t)(__attribute__((address_space(3))) const char*)p;
}
// tanh-form gelu, one v_exp; max |dev| from exact erf-gelu ~7e-4.
__device__ __forceinline__ float gelu_f(float x) {
    float y2 = 1.5957691216057308f * (x + 0.044715f * x * x * x);  // 2*sqrt(2/pi)*(...)
    float e  = __expf(y2);
    float t  = 1.0f - 2.0f / (e + 1.0f);
    return 0.5f * x * (1.0f + t);
}

// window-order row m -> original (b,l) row: roll(-SHIFT) + 7x7 partition.
__device__ __forceinline__ int win2orig(int m) {
    int w = m / 49, t = m - w * 49;
    int b = w >> 6, wi = (w >> 3) & 7, wj = w & 7;
    int ti = t / 7, tj = t - ti * 7;
    int i = wi * 7 + ti + SHIFT; if (i >= HH) i -= HH;
    int j = wj * 7 + tj + SHIFT; if (j >= WWp) j -= WWp;
    return b * L + i * WWp + j;
}

__device__ __forceinline__ void async_copy16(void* ldsdst, const void* gsrc) {
    __builtin_amdgcn_global_load_lds(
        (const __attribute__((address_space(1))) unsigned int*)gsrc,
        (__attribute__((address_space(3))) unsigned int*)ldsdst,
        16, 0, 0);
}

// Weights fp32->bf16 (196608 elems) + bias fragment table (16384 floats).
// biasd layout: [h][lane][mi][ni][r]; -1e30 for j>=49, 0 for i>=49.
__global__ __launch_bounds__(256) void wconv_kernel(
    const float* __restrict__ qkvw, const float* __restrict__ projw,
    const float* __restrict__ fc1w, const float* __restrict__ fc2w,
    const float* __restrict__ rpb, float* __restrict__ biasd,
    unsigned short* __restrict__ wb) {
    int i = blockIdx.x * 256 + threadIdx.x;
    float v;
    if (i < 49152)       v = qkvw[i];
    else if (i < 65536)  v = projw[i - 49152];
    else if (i < 131072) v = fc1w[i - 65536];
    else                 v = fc2w[i - 131072];
    wb[i] = f2bf(v);
    if (i < 16384) {
        int h = i >> 12, l = (i >> 6) & 63, f = i & 63;
        int mi = f >> 4, ni = (f >> 2) & 3, r = f & 3;
        int ii = mi * 16 + (l >> 4) * 4 + r;
        int jj = ni * 16 + (l & 15);
        float bv;
        if (jj >= 49)      bv = -1e30f;
        else if (ii >= 49) bv = 0.f;
        else {
            int yi = ii / 7, xi = ii - yi * 7, yj = jj / 7, xj = jj - yj * 7;
            bv = rpb[((yi - yj + 6) * 13 + (xi - xj + 6)) * NH + h];
        }
        biasd[i] = bv;
    }
}

// LayerNorm over C=128, fp32 in -> bf16 out. 1 wave/row, 4 rows/block.
__global__ __launch_bounds__(256) void ln_kernel(const float* __restrict__ in,
                                                 const float* __restrict__ g,
                                                 const float* __restrict__ bta,
                                                 unsigned short* __restrict__ out) {
    int row  = blockIdx.x * 4 + (threadIdx.x >> 6);
    int lane = threadIdx.x & 63;
    const float2 v = ((const float2*)(in + (long)row * C))[lane];
    float s  = v.x + v.y;
    float ss = v.x * v.x + v.y * v.y;
#pragma unroll
    for (int off = 32; off >= 1; off >>= 1) {
        s  += __shfl_xor(s, off);
        ss += __shfl_xor(ss, off);
    }
    float mu  = s * (1.0f / C);
    float var = ss * (1.0f / C) - mu * mu;
    float rs  = rsqrtf(var + 1e-5f);
    float2 gg = ((const float2*)g)[lane];
    float2 bb = ((const float2*)bta)[lane];
    ushort2 o;
    o.x = f2bf((v.x - mu) * rs * gg.x + bb.x);
    o.y = f2bf((v.y - mu) * rs * gg.y + bb.y);
    ((ushort2*)(out + (long)row * C))[lane] = o;
}

// Pipelined LDS-staged MFMA NT GEMM, OPERAND-SWAPPED: acc = mfma(Wfrag, Afrag)
// so D rows index W (out cols) and each thread's 4 regs are 4 CONSECUTIVE out
// columns -> packed ushort4/float4 epilogue stores.
// 128-row block, 4 waves (2x2), wave = 64(rows) x 64(cols) via 4x4 frags.
// N-tiles loop inside the block (A staged once for K<=128); K in 64-halves,
// stage-before-compute double buffering (one __syncthreads per half).
// Thread (wid: wm,wn; lane: g=lane>>4, lr=lane&15) owns, for (mi,ni,rg):
//   out row m = mbase + wm*64 + mi*16 + lr
//   out col n = nbase + wn*64 + ni*16 + g*4 + rg   (rg consecutive!)
// MODE 0: qkv (gather rows; q scaled; k [wh][49][32]; v^T [wh][32][64])
// MODE 1: proj (+ resid fp32 x; fused LN2 -> x2b AND h2n, scattered rows)
// MODE 2: fc1 (fast gelu; bf16 out)
// MODE 3: fc2 (+ resid bf16 x2b; fp32 out = d_out)
template<int MODE, int K, int NB, bool GATHER>
__global__ __launch_bounds__(256) void gemm_pipe(
    const unsigned short* __restrict__ A,
    const unsigned short* __restrict__ Wb,
    const float* __restrict__ bias,
    const float* __restrict__ residf,
    const unsigned short* __restrict__ residb,
    const float* __restrict__ g2, const float* __restrict__ b2,
    float* __restrict__ outf,
    unsigned short* __restrict__ outb,
    unsigned short* __restrict__ outb2)
{
    constexpr int KH = K / 64;          // K-halves
    constexpr bool BIGK = (K > 128);
    __shared__ char lds[65536];
    char* ldsA = lds;                   // BIGK: dbuf 2x16KB ; else full 32KB
    char* ldsB = lds + 32768;           // dbuf 2x16KB
    const int tid = threadIdx.x;
    const int wid = tid >> 6, lane = tid & 63;
    const int g = lane >> 4, lr = lane & 15;
    const int wm = wid >> 1, wn = wid & 1;
    const int mbase = blockIdx.x * 128;

    auto stageAfull = [&]() {
#pragma unroll
        for (int i = 0; i < 8; ++i) {
            const int c = i * 4 + wid;
            const int r = (c << 2) + (lane >> 4);
            const int s = (lane & 15) ^ (r & 15);
            long arow = GATHER ? (long)win2orig(mbase + r) : (long)(mbase + r);
            async_copy16(ldsA + c * 1024, (const char*)A + arow * (K * 2) + s * 16);
        }
    };
    auto stageAhalf = [&](int buf, int kh) {
#pragma unroll
        for (int i = 0; i < 4; ++i) {
            const int c = i * 4 + wid;
            const int r = (c << 3) + (lane >> 3);
            const int s = (lane & 7) ^ (r & 7);
            async_copy16(ldsA + buf * 16384 + c * 1024,
                         (const char*)A + (long)(mbase + r) * (K * 2) + kh * 128 + s * 16);
        }
    };
    auto stageBhalf = [&](int buf, int nb, int kh) {
#pragma unroll
        for (int i = 0; i < 4; ++i) {
            const int c = i * 4 + wid;
            const int r = (c << 3) + (lane >> 3);
            const int s = (lane & 7) ^ (r & 7);
            async_copy16(ldsB + buf * 16384 + c * 1024,
                         (const char*)Wb + (long)(nb * 128 + r) * (K * 2) + kh * 128 + s * 16);
        }
    };

    if constexpr (!BIGK) stageAfull(); else stageAhalf(0, 0);
    stageBhalf(0, 0, 0);
    __syncthreads();
    int cur = 0;

    for (int nb = 0; nb < NB; ++nb) {
        const int nbase = nb * 128;
        f32x4 acc[4][4] = {};
        for (int kh = 0; kh < KH; ++kh) {
            const bool last = (nb == NB - 1) && (kh == KH - 1);
            if (!last) {
                const int nnb = (kh == KH - 1) ? nb + 1 : nb;
                const int nkh = (kh == KH - 1) ? 0 : kh + 1;
                if constexpr (BIGK) stageAhalf(cur ^ 1, nkh);
                stageBhalf(cur ^ 1, nnb, nkh);
            }
#pragma unroll
            for (int kkh = 0; kkh < 2; ++kkh) {
                bf16x8 af[4], bfr[4];
#pragma unroll
                for (int mi = 0; mi < 4; ++mi) {
                    const int ra = wm * 64 + mi * 16 + lr;
                    if constexpr (BIGK) {
                        af[mi] = *(const bf16x8*)(ldsA + cur * 16384 + ra * 128 + (((kkh * 4 + g) ^ (ra & 7)) * 16));
                    } else {
                        const int kk = kh * 2 + kkh;
                        af[mi] = *(const bf16x8*)(ldsA + ra * 256 + (((kk * 4 + g) ^ (ra & 15)) * 16));
                    }
                }
#pragma unroll
                for (int ni = 0; ni < 4; ++ni) {
                    const int rb = wn * 64 + ni * 16 + lr;
                    bfr[ni] = *(const bf16x8*)(ldsB + cur * 16384 + rb * 128 + (((kkh * 4 + g) ^ (rb & 7)) * 16));
                }
#pragma unroll
                for (int mi = 0; mi < 4; ++mi)
#pragma unroll
                    for (int ni = 0; ni < 4; ++ni)
                        acc[mi][ni] = __builtin_amdgcn_mfma_f32_16x16x32_bf16(bfr[ni], af[mi], acc[mi][ni], 0, 0, 0);
            }
            if (!last) { __syncthreads(); cur ^= 1; }
        }

        // ---- Epilogue for this nb (swapped layout) ----
        if constexpr (MODE == 0) {
            const int prt = nb;   // within-block n range is exactly 128
#pragma unroll
            for (int mi = 0; mi < 4; ++mi) {
                const int gm = mbase + wm * 64 + mi * 16 + lr;
                const int w = gm / 49, t = gm - w * 49;
#pragma unroll
                for (int ni = 0; ni < 4; ++ni) {
                    const int nloc = wn * 64 + ni * 16 + g * 4;
                    const int hh = nloc >> 5, dd = nloc & 31;
                    const f32x4 b4 = *(const f32x4*)&bias[nbase + nloc];
                    if (prt == 2) {
                        const long dbase = 2L * M * 128 + (((long)(w * 4 + hh)) * 32 + dd) * 64 + t;
#pragma unroll
                        for (int rg = 0; rg < 4; ++rg)
                            outb[dbase + rg * 64] = f2bf(acc[mi][ni][rg] + b4[rg]);
                    } else {
                        const float sc = (prt == 0) ? 0.17677669529663687f : 1.0f;
                        ushort4 pw;
                        pw.x = f2bf((acc[mi][ni][0] + b4[0]) * sc);
                        pw.y = f2bf((acc[mi][ni][1] + b4[1]) * sc);
                        pw.z = f2bf((acc[mi][ni][2] + b4[2]) * sc);
                        pw.w = f2bf((acc[mi][ni][3] + b4[3]) * sc);
                        *(ushort4*)(outb + (long)prt * M * 128 + (((long)(w * 4 + hh)) * 49 + t) * 32 + dd) = pw;
                    }
                }
            }
        } else if constexpr (MODE == 1) {
            // x2 = x + (o@W + b); then LN2 in-register (NB==1, full C rows).
            // Thread rows: r64 = mi*16+lr (4 rows); 16 cols each (ni x rg).
            int rr[4];
#pragma unroll
            for (int mi = 0; mi < 4; ++mi)
                rr[mi] = win2orig(mbase + wm * 64 + mi * 16 + lr);
#pragma unroll
            for (int mi = 0; mi < 4; ++mi)
#pragma unroll
                for (int ni = 0; ni < 4; ++ni) {
                    const int nloc = wn * 64 + ni * 16 + g * 4;
                    const f32x4 b4 = *(const f32x4*)&bias[nloc];
                    const f32x4 r4 = *(const f32x4*)&residf[(long)rr[mi] * C + nloc];
                    acc[mi][ni] += b4 + r4;
                }
            float sA[4], qA[4];
#pragma unroll
            for (int mi = 0; mi < 4; ++mi) {
                float s = 0.f, q = 0.f;
#pragma unroll
                for (int ni = 0; ni < 4; ++ni)
#pragma unroll
                    for (int rg = 0; rg < 4; ++rg) {
                        float v = acc[mi][ni][rg];
                        s += v; q += v * v;
                    }
                s += __shfl_xor(s, 16); q += __shfl_xor(q, 16);
                s += __shfl_xor(s, 32); q += __shfl_xor(q, 32);
                sA[mi] = s; qA[mi] = q;
            }
            float* lp = (float*)lds;    // reuse: [wm][64][wn][2] = 512 floats
            __syncthreads();
            if (g == 0) {
#pragma unroll
                for (int mi = 0; mi < 4; ++mi) {
                    const int r64 = mi * 16 + lr;
                    lp[((wm * 64 + r64) * 2 + wn) * 2 + 0] = sA[mi];
                    lp[((wm * 64 + r64) * 2 + wn) * 2 + 1] = qA[mi];
                }
            }
            __syncthreads();
#pragma unroll
            for (int mi = 0; mi < 4; ++mi) {
                const int r64 = mi * 16 + lr;
                const float st = sA[mi] + lp[((wm * 64 + r64) * 2 + (wn ^ 1)) * 2 + 0];
                const float qt = qA[mi] + lp[((wm * 64 + r64) * 2 + (wn ^ 1)) * 2 + 1];
                const float mu = st * (1.0f / C);
                const float var = qt * (1.0f / C) - mu * mu;
                const float rs = rsqrtf(var + 1e-5f);
                const long rbase = (long)rr[mi] * C;
#pragma unroll
                for (int ni = 0; ni < 4; ++ni) {
                    const int nloc = wn * 64 + ni * 16 + g * 4;
                    ushort4 px, ph;
#pragma unroll
                    for (int rg = 0; rg < 4; ++rg) {
                        const float xv = acc[mi][ni][rg];
                        const float hv = (xv - mu) * rs * g2[nloc + rg] + b2[nloc + rg];
                        ((unsigned short*)&px)[rg] = f2bf(xv);
                        ((unsigned short*)&ph)[rg] = f2bf(hv);
                    }
                    *(ushort4*)(outb2 + rbase + nloc) = px;
                    *(ushort4*)(outb  + rbase + nloc) = ph;
                }
            }
        } else if constexpr (MODE == 2) {
#pragma unroll
            for (int mi = 0; mi < 4; ++mi) {
                const long gm = mbase + wm * 64 + mi * 16 + lr;
#pragma unroll
                for (int ni = 0; ni < 4; ++ni) {
                    const int n0 = nbase + wn * 64 + ni * 16 + g * 4;
                    const f32x4 b4 = *(const f32x4*)&bias[n0];
                    ushort4 pw;
                    pw.x = f2bf(gelu_f(acc[mi][ni][0] + b4[0]));
                    pw.y = f2bf(gelu_f(acc[mi][ni][1] + b4[1]));
                    pw.z = f2bf(gelu_f(acc[mi][ni][2] + b4[2]));
                    pw.w = f2bf(gelu_f(acc[mi][ni][3] + b4[3]));
                    *(ushort4*)(outb + gm * HID + n0) = pw;
                }
            }
        } else {
#pragma unroll
            for (int mi = 0; mi < 4; ++mi) {
                const long gm = mbase + wm * 64 + mi * 16 + lr;
#pragma unroll
                for (int ni = 0; ni < 4; ++ni) {
                    const int n0 = wn * 64 + ni * 16 + g * 4;
                    const f32x4 b4 = *(const f32x4*)&bias[n0];
                    const ushort4 r4 = *(const ushort4*)(residb + gm * C + n0);
                    f32x4 o4;
                    o4[0] = acc[mi][ni][0] + b4[0] + bf2f(r4.x);
                    o4[1] = acc[mi][ni][1] + b4[1] + bf2f(r4.y);
                    o4[2] = acc[mi][ni][2] + b4[2] + bf2f(r4.z);
                    o4[3] = acc[mi][ni][3] + b4[3] + bf2f(r4.w);
                    *(f32x4*)(outf + gm * C + n0) = o4;
                }
            }
        }
    }
}

// MFMA attention: 1 block/window, 1 wave/head (unchanged, proven round 3).
__global__ __launch_bounds__(256) void attn_mfma(
    const unsigned short* __restrict__ qb,   // [wh][49][32], pre-scaled
    const unsigned short* __restrict__ kb,   // [wh][49][32]
    const unsigned short* __restrict__ vtb,  // [wh][32][64] (V^T)
    const float* __restrict__ biasd,         // [h][lane][mi][ni][r]
    unsigned short* __restrict__ ob)         // [w*49+t][128]
{
    __shared__ __align__(16) char Pt[4][8192];
    const int tid  = threadIdx.x;
    const int h    = tid >> 6;
    const int lane = tid & 63;
    const int g    = lane >> 4, lr = lane & 15;
    const int w    = blockIdx.x;
    const long wh  = (long)(w * 4 + h);
    const unsigned short* qp = qb  + wh * (49 * 32);
    const unsigned short* kp = kb  + wh * (49 * 32);
    const unsigned short* vp = vtb + wh * (32 * 64);

    bf16x8 qf[4], kf[4];
#pragma unroll
    for (int mi = 0; mi < 4; ++mi) {
        qf[mi] = *(const bf16x8*)(qp + (mi * 16 + lr) * 32 + g * 8);
        kf[mi] = *(const bf16x8*)(kp + (mi * 16 + lr) * 32 + g * 8);
    }
    f32x4 acc[4][4] = {};
#pragma unroll
    for (int mi = 0; mi < 4; ++mi)
#pragma unroll
        for (int ni = 0; ni < 4; ++ni)
            acc[mi][ni] = __builtin_amdgcn_mfma_f32_16x16x32_bf16(qf[mi], kf[ni], acc[mi][ni], 0, 0, 0);

    const float* bp = biasd + (h * 64 + lane) * 64;
    char* ptw = &Pt[h][0];
#pragma unroll
    for (int mi = 0; mi < 4; ++mi) {
#pragma unroll
        for (int ni = 0; ni < 4; ++ni)
            acc[mi][ni] += *(const f32x4*)(bp + mi * 16 + ni * 4);
#pragma unroll
        for (int c = 0; c < 4; ++c)
            acc[mi][3][c] = (lr == 0) ? acc[mi][3][c] : -1e30f;
        f32x4 mx;
#pragma unroll
        for (int c = 0; c < 4; ++c)
            mx[c] = fmaxf(fmaxf(acc[mi][0][c], acc[mi][1][c]), fmaxf(acc[mi][2][c], acc[mi][3][c]));
#pragma unroll
        for (int off = 1; off <= 8; off <<= 1)
#pragma unroll
            for (int c = 0; c < 4; ++c)
                mx[c] = fmaxf(mx[c], __shfl_xor(mx[c], off));
        f32x4 sum = {};
#pragma unroll
        for (int ni = 0; ni < 4; ++ni)
#pragma unroll
            for (int c = 0; c < 4; ++c) {
                float e = __expf(acc[mi][ni][c] - mx[c]);
                acc[mi][ni][c] = e;
                sum[c] += e;
            }
#pragma unroll
        for (int off = 1; off <= 8; off <<= 1)
#pragma unroll
            for (int c = 0; c < 4; ++c)
                sum[c] += __shfl_xor(sum[c], off);
        f32x4 inv;
#pragma unroll
        for (int c = 0; c < 4; ++c)
            inv[c] = __builtin_amdgcn_rcpf(sum[c]);
#pragma unroll
        for (int ni = 0; ni < 4; ++ni) {
            ushort4 pw;
            pw.x = f2bf(acc[mi][ni][0] * inv[0]);
            pw.y = f2bf(acc[mi][ni][1] * inv[1]);
            pw.z = f2bf(acc[mi][ni][2] * inv[2]);
            pw.w = f2bf(acc[mi][ni][3] * inv[3]);
            int jb  = ni * 4 + (lr >> 2);
            int tix = (((jb >> 3) * 2 + (jb & 1)) * 4 + mi) * 4 + ((jb >> 1) & 3);
            *(ushort4*)(ptw + tix * 128 + (lr & 3) * 32 + g * 8) = pw;
        }
    }
    __syncthreads();

    bf16x8 vf[2][2];
#pragma unroll
    for (int md = 0; md < 2; ++md) {
#pragma unroll
        for (int kk = 0; kk < 2; ++kk)
            vf[md][kk] = *(const bf16x8*)(vp + (md * 16 + lr) * 64 + kk * 32 + g * 8);
#pragma unroll
        for (int e = 0; e < 8; ++e)
            if (g * 8 + e > 16) vf[md][1][e] = (__bf16)0.0f;
    }

    const unsigned pbase = lds_addr(&Pt[h][0]);
    f32x4 accO[2][4] = {};
#pragma unroll
    for (int kk = 0; kk < 2; ++kk) {
        long tt[4][2];
#pragma unroll
        for (int ni = 0; ni < 4; ++ni)
#pragma unroll
            for (int s = 0; s < 2; ++s) {
                unsigned a = pbase + ((((kk * 2 + s) * 4 + ni) * 4 + g) * 128) + lr * 2;
                asm volatile("ds_read_b64_tr_b16 %0, %1" : "=v"(tt[ni][s]) : "v"(a));
            }
        asm volatile("s_waitcnt lgkmcnt(0)" ::: "memory");
        __builtin_amdgcn_sched_barrier(0);
#pragma unroll
        for (int ni = 0; ni < 4; ++ni) {
            union { int4 i4; bf16x8 v; } u;
            u.i4 = make_int4((int)tt[ni][0], (int)(tt[ni][0] >> 32),
                             (int)tt[ni][1], (int)(tt[ni][1] >> 32));
#pragma unroll
            for (int md = 0; md < 2; ++md)
                accO[md][ni] = __builtin_amdgcn_mfma_f32_16x16x32_bf16(vf[md][kk], u.v, accO[md][ni], 0, 0, 0);
        }
    }
#pragma unroll
    for (int ni = 0; ni < 4; ++ni) {
        int i = ni * 16 + lr;
        if (i < 49) {
#pragma unroll
            for (int md = 0; md < 2; ++md) {
                ushort4 ov;
                ov.x = f2bf(accO[md][ni][0]);
                ov.y = f2bf(accO[md][ni][1]);
                ov.z = f2bf(accO[md][ni][2]);
                ov.w = f2bf(accO[md][ni][3]);
                *(ushort4*)(ob + ((long)(w * 49 + i)) * 128 + h * 32 + md * 16 + g * 4) = ov;
            }
        }
    }
}

extern "C" void kernel_launch(void* const* d_in, const int* in_sizes, int n_in,
                              void* d_out, int out_size, void* d_ws, size_t ws_size,
                              hipStream_t stream) {
    const float* x      = (const float*)d_in[0];
    const float* n1g    = (const float*)d_in[1];
    const float* n1b    = (const float*)d_in[2];
    const float* qkv_w  = (const float*)d_in[3];
    const float* qkv_b  = (const float*)d_in[4];
    const float* proj_w = (const float*)d_in[5];
    const float* proj_b = (const float*)d_in[6];
    const float* rpb    = (const float*)d_in[7];
    const float* n2g    = (const float*)d_in[8];
    const float* n2b    = (const float*)d_in[9];
    const float* fc1_w  = (const float*)d_in[10];
    const float* fc1_b  = (const float*)d_in[11];
    const float* fc2_w  = (const float*)d_in[12];
    const float* fc2_b  = (const float*)d_in[13];
    float* out = (float*)d_out;

    // Workspace (~324 MB):
    //  [0,SZ)             hnorm -> o -> h2[0:..]
    //  [SZ,3SZ+VT)        q | k | v^T
    //  [3SZ+VT, 4SZ+VT)   x2b bf16
    //  [4SZ+VT, 5SZ+VT)   h2n
    //  [5SZ+VT, ..)       weights bf16 (384KB) + biasd (64KB)
    //  h2 = [0,4SZ)  (regions dead by fc1 time)
    char* ws = (char*)d_ws;
    const size_t SZ = (size_t)M * C * 2;                    // 51,380,224
    const size_t VT = (size_t)NWIN * NH * 32 * 64 * 2;      // 67,108,864
    unsigned short* hnorm  = (unsigned short*)(ws);
    unsigned short* qkvbuf = (unsigned short*)(ws + SZ);
    unsigned short* o      = hnorm;
    unsigned short* x2b    = (unsigned short*)(ws + 3 * SZ + VT);
    unsigned short* h2n    = (unsigned short*)(ws + 4 * SZ + VT);
    unsigned short* h2     = (unsigned short*)(ws);
    unsigned short* wb     = (unsigned short*)(ws + 5 * SZ + VT);
    float* biasd           = (float*)(ws + 5 * SZ + VT + 393216);
    unsigned short* wqkv = wb, *wproj = wb + 49152, *wfc1 = wb + 65536, *wfc2 = wb + 131072;

    wconv_kernel<<<768, 256, 0, stream>>>(qkv_w, proj_w, fc1_w, fc2_w, rpb, biasd, wb);
    ln_kernel<<<M / 4, 256, 0, stream>>>(x, n1g, n1b, hnorm);
    gemm_pipe<0, 128, 3, true ><<<M / 128, 256, 0, stream>>>(hnorm, wqkv, qkv_b, nullptr, nullptr, nullptr, nullptr, nullptr, qkvbuf, nullptr);
    attn_mfma<<<NWIN, 256, 0, stream>>>(qkvbuf, qkvbuf + (size_t)M * 128, qkvbuf + 2 * (size_t)M * 128, biasd, o);
    gemm_pipe<1, 128, 1, false><<<M / 128, 256, 0, stream>>>(o, wproj, proj_b, x, nullptr, n2g, n2b, nullptr, h2n, x2b);
    gemm_pipe<2, 128, 4, false><<<M / 128, 256, 0, stream>>>(h2n, wfc1, fc1_b, nullptr, nullptr, nullptr, nullptr, nullptr, h2, nullptr);
    gemm_pipe<3, 512, 1, false><<<M / 128, 256, 0, stream>>>(h2, wfc2, fc2_b, nullptr, x2b, nullptr, nullptr, out, nullptr, nullptr);
}